// Round 11
// baseline (258.200 us; speedup 1.0000x reference)
//
#include <hip/hip_runtime.h>
#include <math.h>

// Problem constants
#define NPIX   131072      // 32 * 64 * 64 pixels
#define KCODES 512
#define DDIM   64
#define HWSZ   4096        // 64*64
#define NELEM  8388608     // NPIX * DDIM

// d_out layout (fp32): [0]=loss, [1..1+NELEM)=q_nchw, [1+NELEM]=perplexity,
// [2+NELEM .. 2+2*NELEM)=q_nhwc flat
#define OUT_NCHW_OFF 1
#define OUT_PERP_IDX (1 + NELEM)
#define OUT_NHWC_OFF (2 + NELEM)

// ws layout (fp32 words): [0]=loss, [16..528)=|e|^2, [544..1056)=counts(uint),
// [2048..) = e bf16 hi/lo fragments in MFMA B-layout (byte 8192, 128KB)
#define WS_NRM_OFF  16
#define WS_CNT_OFF  544
#define WS_FRAG_F32 2048

#define BLKTHREADS 128               // 2 waves/block, 64 px/wave (pt=4)
#define NBLOCKS (NPIX / BLKTHREADS)  // 1024 blocks

typedef __bf16 bf16x8 __attribute__((ext_vector_type(8)));
typedef float  f32x4  __attribute__((ext_vector_type(4)));

// Fused prep (memset + norms + pack in one dispatch; proven R2-R10). Thread
// tid = [ctile(32)][kstep(2)][h(2)][lane(64)] packs e into bf16 hi/lo MFMA
// B-fragments (16x16x32: B[k][n], n=lane&15, k=(lane>>4)*8+j); 16B coalesced.
// tid<512 computes |e|^2; tid in [512,1024) zeros counts; tid 0 zeros loss.
__global__ __launch_bounds__(256) void vq_prep(const float* __restrict__ emb,
                                               float* __restrict__ ws) {
    int tid  = blockIdx.x * 256 + threadIdx.x;   // 0..8191
    if (tid == 0) ws[0] = 0.f;
    if (tid < KCODES) {
        const float4* e4 = reinterpret_cast<const float4*>(emb + tid * DDIM);
        float s = 0.f;
#pragma unroll
        for (int i = 0; i < 16; ++i) {
            float4 v = e4[i];
            s = fmaf(v.x, v.x, s); s = fmaf(v.y, v.y, s);
            s = fmaf(v.z, v.z, s); s = fmaf(v.w, v.w, s);
        }
        ws[WS_NRM_OFF + tid] = s;
    } else if (tid < 2 * KCODES) {
        reinterpret_cast<unsigned*>(ws)[WS_CNT_OFF + (tid - KCODES)] = 0u;
    }

    int lane = tid & 63;
    int h    = (tid >> 6) & 1;
    int ks   = (tid >> 7) & 1;
    int ct   = tid >> 8;                         // 0..31
    int code = ct * 16 + (lane & 15);
    int d0   = ks * 32 + ((lane >> 4) & 3) * 8;
    const float* src = emb + code * DDIM + d0;
    unsigned short us[8];
#pragma unroll
    for (int j = 0; j < 8; ++j) {
        float f = src[j];
        __bf16 hb = (__bf16)f;                       // RTN
        if (h == 0) {
            us[j] = __builtin_bit_cast(unsigned short, hb);
        } else {
            __bf16 lb = (__bf16)(f - (float)hb);
            us[j] = __builtin_bit_cast(unsigned short, lb);
        }
    }
    uint4 v;
    v.x = us[0] | ((unsigned)us[1] << 16);
    v.y = us[2] | ((unsigned)us[3] << 16);
    v.z = us[4] | ((unsigned)us[5] << 16);
    v.w = us[6] | ((unsigned)us[7] << 16);
    reinterpret_cast<uint4*>(ws + WS_FRAG_F32)[tid] = v;
}

// One code-chunk (32 codes): optional prefetch of next chunk's B-frags into
// BNXT, then 64 MFMA (4-term bf16 hi/lo split, setprio(1) around the MFMA
// cluster), then argmin update. Inlined with named arrays at both call sites
// -> all indexing static (no scratch). Proven R9 (+3.5us vs R8). UNCHANGED.
__device__ __forceinline__ void vq_chunk(
    int cc, bool dopf, const uint4* __restrict__ fragp, int l,
    uint4 (&bcur)[8], uint4 (&bnxt)[8],
    const bf16x8 (&a_hi)[4][2], const bf16x8 (&a_lo)[4][2],
    const float* __restrict__ nrm_lds,
    float (&best)[4][4], int (&bidx)[4][4]) {
    if (dopf) {
        const int ctb = (cc + 1) << 1;
#pragma unroll
        for (int i = 0; i < 8; ++i) {
            int ct = i >> 2, ks = (i >> 1) & 1, h = i & 1;
            bnxt[i] = fragp[(((ctb + ct) * 2 + ks) * 2 + h) * 64 + l];
        }
    }
    // 64 pix x 32 codes: 8 C-tiles, 4-term bf16 split accumulated in fp32
    f32x4 acc[4][2];
    __builtin_amdgcn_s_setprio(1);
#pragma unroll
    for (int pt = 0; pt < 4; ++pt)
#pragma unroll
    for (int ct = 0; ct < 2; ++ct) {
        f32x4 a = {0.f, 0.f, 0.f, 0.f};
#pragma unroll
        for (int ks = 0; ks < 2; ++ks) {
            bf16x8 bh = __builtin_bit_cast(bf16x8, bcur[ct * 4 + ks * 2 + 0]);
            bf16x8 bl = __builtin_bit_cast(bf16x8, bcur[ct * 4 + ks * 2 + 1]);
            a = __builtin_amdgcn_mfma_f32_16x16x32_bf16(a_hi[pt][ks], bh, a, 0, 0, 0);
            a = __builtin_amdgcn_mfma_f32_16x16x32_bf16(a_hi[pt][ks], bl, a, 0, 0, 0);
            a = __builtin_amdgcn_mfma_f32_16x16x32_bf16(a_lo[pt][ks], bh, a, 0, 0, 0);
            a = __builtin_amdgcn_mfma_f32_16x16x32_bf16(a_lo[pt][ks], bl, a, 0, 0, 0);
        }
        acc[pt][ct] = a;
    }
    __builtin_amdgcn_s_setprio(0);
    // argmin update; C/D: col(code)=lane&15, row(pix)=(lane>>4)*4+reg
    const int cb = cc << 5;
#pragma unroll
    for (int ct = 0; ct < 2; ++ct) {
        int code = cb + ct * 16 + (l & 15);
        float nv = nrm_lds[code];
#pragma unroll
        for (int pt = 0; pt < 4; ++pt)
#pragma unroll
        for (int r = 0; r < 4; ++r) {
            float d = fmaf(-2.f, acc[pt][ct][r], nv);
            if (d < best[pt][r]) { best[pt][r] = d; bidx[pt][r] = code; }
        }
    }
}

// Main — R11: genuinely raise the resident-wave cap. R10's error: 4 blk/CU x
// 2 waves = same 8-wave cap as R9 (occupancy counter confirmed, 16.4%). The
// LDS blocker is the xs staging tile; R5 PROVED on hardware (same absmax
// 3.71875) that direct-global A-fragment loads + shuffle-x2 are bit-identical
// to the staged path. Dropping xs: LDS ~22KB -> 7 blocks/CU = 14 waves/CU
// (first config above 8), with the proven chunk loop (pt=4, ping-pong B,
// setprio) token-identical. (128,4) caps VGPR at 128; R5's direct-A code was
// 104 VGPR -> no spill expected (spill alarm = WRITE_SIZE balloon).
// R10's atomic tax mitigated: zero-count bins skipped in global merge
// (>=75% fewer count atomics at 128px/block; bit-exact counts).
__global__ __launch_bounds__(128, 4) void vq_main(const float* __restrict__ in,
                                                  const float* __restrict__ emb,
                                                  float* __restrict__ out,
                                                  float* __restrict__ ws) {
    __shared__ __align__(16) float q_lds[64 * 65];   // epilogue transpose tile
    __shared__ float    x2_lds[128];
    __shared__ float    nrm_lds[KCODES];
    __shared__ int      idx_lds[128];
    __shared__ unsigned cnt_lds[KCODES];
    __shared__ float    red_tot;

    const int t = threadIdx.x;            // 0..127
    const int l = t & 63, wid = t >> 6;   // 2 waves; wave owns px [wid*64,+64)
    cnt_lds[t]       = 0u; cnt_lds[t + 128] = 0u;
    cnt_lds[t + 256] = 0u; cnt_lds[t + 384] = 0u;
    if (t == 0) red_tot = 0.f;

    const int pix0 = blockIdx.x << 7;     // 128 px per block
    const int b    = pix0 >> 12;
    const int hwb  = pix0 & (HWSZ - 1);

    nrm_lds[t]       = ws[WS_NRM_OFF + t];
    nrm_lds[t + 128] = ws[WS_NRM_OFF + t + 128];
    nrm_lds[t + 256] = ws[WS_NRM_OFF + t + 256];
    nrm_lds[t + 384] = ws[WS_NRM_OFF + t + 384];

    // A-fragments (A[m][k]: m=lane&15, k=(lane>>4)*8+j), hi/lo bf16 split,
    // loaded DIRECTLY from global NCHW (R5-proven bit-identical; each
    // (pixel,channel) read exactly once per wave). |x|^2 via xor-16/32
    // reduce: lanes l, l^16, l^32, l^48 cover all 64 channels of pixel hw.
    const float* base = in + b * (DDIM * HWSZ) + hwb + wid * 64;
    bf16x8 a_hi[4][2], a_lo[4][2];
    float x2p[4];
#pragma unroll
    for (int pt = 0; pt < 4; ++pt) {
        const int hw = pt * 16 + (l & 15);
        float s = 0.f;
#pragma unroll
        for (int ks = 0; ks < 2; ++ks) {
            const int d0 = ks * 32 + ((l >> 4) & 3) * 8;
            const float* pp = base + hw + d0 * HWSZ;
            bf16x8 h8, l8;
#pragma unroll
            for (int j = 0; j < 8; ++j) {
                float f = pp[j * HWSZ];
                s = fmaf(f, f, s);
                __bf16 hb = (__bf16)f;
                h8[j] = hb;
                l8[j] = (__bf16)(f - (float)hb);
            }
            a_hi[pt][ks] = h8; a_lo[pt][ks] = l8;
        }
        s += __shfl_xor(s, 16, 64);
        s += __shfl_xor(s, 32, 64);
        x2p[pt] = s;
    }
    if (l < 16) {
#pragma unroll
        for (int pt = 0; pt < 4; ++pt) x2_lds[wid * 64 + pt * 16 + l] = x2p[pt];
    }

    const uint4* fragp = reinterpret_cast<const uint4*>(ws + WS_FRAG_F32);
    float best[4][4]; int bidx[4][4];
#pragma unroll
    for (int pt = 0; pt < 4; ++pt)
#pragma unroll
    for (int r = 0; r < 4; ++r) { best[pt][r] = 3.4e38f; bidx[pt][r] = 0; }

    // B-frag ping-pong init issued before the barrier (global loads,
    // independent of LDS) so they're in flight during the sync.
    uint4 b0[8], b1[8];
#pragma unroll
    for (int i = 0; i < 8; ++i) {
        int ct = i >> 2, ks = (i >> 1) & 1, h = i & 1;
        b0[i] = fragp[(((ct) * 2 + ks) * 2 + h) * 64 + l];
    }
    __syncthreads();   // nrm_lds/x2_lds/cnt_lds visible to both waves

#pragma unroll 1
    for (int c = 0; c < 16; c += 2) {
        vq_chunk(c,     true,         fragp, l, b0, b1, a_hi, a_lo, nrm_lds, best, bidx);
        vq_chunk(c + 1, (c + 1) < 15, fragp, l, b1, b0, a_hi, a_lo, nrm_lds, best, bidx);
    }

    // Cross-lane argmin within each 16-lane group (codes spread over lane&15);
    // (dist, then idx) min = exact first-min semantics.
#pragma unroll
    for (int off = 1; off < 16; off <<= 1) {
#pragma unroll
        for (int pt = 0; pt < 4; ++pt)
#pragma unroll
        for (int r = 0; r < 4; ++r) {
            float ob = __shfl_xor(best[pt][r], off, 64);
            int   oi = __shfl_xor(bidx[pt][r], off, 64);
            bool take = (ob < best[pt][r]) || (ob == best[pt][r] && oi < bidx[pt][r]);
            if (take) { best[pt][r] = ob; bidx[pt][r] = oi; }
        }
    }
    if ((l & 15) == 0) {
        int q = l >> 4;
        float lp = 0.f;
#pragma unroll
        for (int pt = 0; pt < 4; ++pt)
#pragma unroll
        for (int r = 0; r < 4; ++r) {
            int pixl = wid * 64 + pt * 16 + q * 4 + r;
            idx_lds[pixl] = bidx[pt][r];
            atomicAdd(&cnt_lds[bidx[pt][r]], 1u);
            lp += x2_lds[pixl] + best[pt][r];   // |x-e|^2 = x^2 + (|e|^2 - 2x.e)
        }
        atomicAdd(&red_tot, lp);
    }
    __syncthreads();

    // Relaxed global atomics issued before the epilogue (R0 ordering): drain
    // at the first epilogue barrier, overlapped with the gather phase.
    // Zero-count bins skipped: >=75% fewer atomics (<=128 of 512 nonzero).
    if (t == 0) atomicAdd(ws, red_tot);
    unsigned* gcnt = reinterpret_cast<unsigned*>(ws) + WS_CNT_OFF;
#pragma unroll
    for (int i = 0; i < 4; ++i) {
        unsigned cv = cnt_lds[t + i * 128];
        if (cv) atomicAdd(gcnt + t + i * 128, cv);
    }

    // Epilogue (R10-proven 128-thread tiling, passes bit-exact): padded LDS
    // tile makes both NHWC and NCHW writes coalesced and conflict-free.
    float* out2 = out + OUT_NCHW_OFF;   // NCHW
    float* out3 = out + OUT_NHWC_OFF;   // NHWC flat (float2-aligned)
    const float2* emb2 = reinterpret_cast<const float2*>(emb);
    float2* out3_2 = reinterpret_cast<float2*>(out3);

    for (int s = 0; s < 2; ++s) {       // 2 slices of 64 px
#pragma unroll
        for (int it = 0; it < 16; ++it) {
            int fid = it * 128 + t;     // 64 px x 32 float2 = 2048
            int pp  = fid >> 5;
            int c2  = fid & 31;
            int row = idx_lds[s * 64 + pp];
            float2 v = emb2[row * 32 + c2];
            out3_2[(size_t)(pix0 + s * 64 + pp) * 32 + c2] = v;
            q_lds[pp * 65 + c2 * 2 + 0] = v.x;
            q_lds[pp * 65 + c2 * 2 + 1] = v.y;
        }
        __syncthreads();
#pragma unroll
        for (int it = 0; it < 32; ++it) {
            int did = it * 128 + t;     // 64 ch x 64 px = 4096
            int c   = did >> 6;
            int hwl = did & 63;
            out2[(size_t)(b * DDIM + c) * HWSZ + hwb + s * 64 + hwl] = q_lds[hwl * 65 + c];
        }
        __syncthreads();
    }
}

__global__ __launch_bounds__(256) void vq_fin(float* __restrict__ out,
                                              const float* __restrict__ ws) {
    const unsigned* cnt = reinterpret_cast<const unsigned*>(ws) + WS_CNT_OFF;
    int t = threadIdx.x;  // 256
    double s = 0.0;
#pragma unroll
    for (int k = t; k < KCODES; k += 256) {
        double p = (double)cnt[k] / (double)NPIX;
        s += p * log(p + 1e-10);
    }
#pragma unroll
    for (int o = 32; o > 0; o >>= 1) s += __shfl_xor(s, o, 64);
    __shared__ double rd[4];
    if ((t & 63) == 0) rd[t >> 6] = s;
    __syncthreads();
    if (t == 0) {
        double tot = rd[0] + rd[1] + rd[2] + rd[3];
        out[OUT_PERP_IDX] = (float)exp(-tot);
        out[0] = 0.25f * ws[0] / (float)NELEM;
    }
}

extern "C" void kernel_launch(void* const* d_in, const int* in_sizes, int n_in,
                              void* d_out, int out_size, void* d_ws, size_t ws_size,
                              hipStream_t stream) {
    const float* in  = (const float*)d_in[0];
    const float* emb = (const float*)d_in[1];
    float* out = (float*)d_out;
    float* ws  = (float*)d_ws;

    // vq_prep zeroes loss+counts and overwrites norms + frag region:
    // no memset dispatch needed. Kernel boundaries provide cross-block
    // ordering (in-kernel tickets proven to cost 15-30us, R6/R7).
    vq_prep<<<32, 256, 0, stream>>>(emb, ws);
    vq_main<<<NBLOCKS, BLKTHREADS, 0, stream>>>(in, emb, out, ws);
    vq_fin<<<1, 256, 0, stream>>>(out, ws);
}

// Round 13
// 128.987 us; speedup vs baseline: 2.0018x; 2.0018x over previous
//
#include <hip/hip_runtime.h>
#include <math.h>

// Problem constants
#define NPIX   131072      // 32 * 64 * 64 pixels
#define KCODES 512
#define DDIM   64
#define HWSZ   4096        // 64*64
#define NELEM  8388608     // NPIX * DDIM

// d_out layout (fp32): [0]=loss, [1..1+NELEM)=q_nchw, [1+NELEM]=perplexity,
// [2+NELEM .. 2+2*NELEM)=q_nhwc flat
#define OUT_NCHW_OFF 1
#define OUT_PERP_IDX (1 + NELEM)
#define OUT_NHWC_OFF (2 + NELEM)

// ws layout (fp32 words): [0]=loss, [16..528)=|e|^2, [544..1056)=counts(uint),
// [2048..) = e bf16 hi/lo fragments in MFMA B-layout (byte 8192, 128KB)
#define WS_NRM_OFF  16
#define WS_CNT_OFF  544
#define WS_FRAG_F32 2048

#define NBLOCKS (NPIX / 256)   // 512 blocks, 256 pixels each (R9 geometry)

typedef __bf16 bf16x8 __attribute__((ext_vector_type(8)));
typedef float  f32x4  __attribute__((ext_vector_type(4)));

// Fused prep (memset + norms + pack in one dispatch; proven R2-R11). Thread
// tid = [ctile(32)][kstep(2)][h(2)][lane(64)] packs e into bf16 hi/lo MFMA
// B-fragments (16x16x32: B[k][n], n=lane&15, k=(lane>>4)*8+j); 16B coalesced.
// tid<512 computes |e|^2; tid in [512,1024) zeros counts; tid 0 zeros loss.
__global__ __launch_bounds__(256) void vq_prep(const float* __restrict__ emb,
                                               float* __restrict__ ws) {
    int tid  = blockIdx.x * 256 + threadIdx.x;   // 0..8191
    if (tid == 0) ws[0] = 0.f;
    if (tid < KCODES) {
        const float4* e4 = reinterpret_cast<const float4*>(emb + tid * DDIM);
        float s = 0.f;
#pragma unroll
        for (int i = 0; i < 16; ++i) {
            float4 v = e4[i];
            s = fmaf(v.x, v.x, s); s = fmaf(v.y, v.y, s);
            s = fmaf(v.z, v.z, s); s = fmaf(v.w, v.w, s);
        }
        ws[WS_NRM_OFF + tid] = s;
    } else if (tid < 2 * KCODES) {
        reinterpret_cast<unsigned*>(ws)[WS_CNT_OFF + (tid - KCODES)] = 0u;
    }

    int lane = tid & 63;
    int h    = (tid >> 6) & 1;
    int ks   = (tid >> 7) & 1;
    int ct   = tid >> 8;                         // 0..31
    int code = ct * 16 + (lane & 15);
    int d0   = ks * 32 + ((lane >> 4) & 3) * 8;
    const float* src = emb + code * DDIM + d0;
    unsigned short us[8];
#pragma unroll
    for (int j = 0; j < 8; ++j) {
        float f = src[j];
        __bf16 hb = (__bf16)f;                       // RTN
        if (h == 0) {
            us[j] = __builtin_bit_cast(unsigned short, hb);
        } else {
            __bf16 lb = (__bf16)(f - (float)hb);
            us[j] = __builtin_bit_cast(unsigned short, lb);
        }
    }
    uint4 v;
    v.x = us[0] | ((unsigned)us[1] << 16);
    v.y = us[2] | ((unsigned)us[3] << 16);
    v.z = us[4] | ((unsigned)us[5] << 16);
    v.w = us[6] | ((unsigned)us[7] << 16);
    reinterpret_cast<uint4*>(ws + WS_FRAG_F32)[tid] = v;
}

// One code-chunk (32 codes): optional prefetch of next chunk's B-frags into
// BNXT, then 64 MFMA with SPLIT ACCUMULATORS (R13): accP takes the hi-A
// terms, accQ the lo-A terms -> 16 independent chains of depth 4 instead of
// 8 chains of depth 8. Occupancy is structurally pinned at 2 waves/SIMD
// (2048 waves total / 256 CU — R11 post-mortem), so the +32 VGPRs are free
// under (256,2)'s 256-reg cap. dot = accP + accQ (one vector add per acc);
// summation regrouping is ~1-ulp fp32 — argmin flips need a <1e-6 distance
// tie (expected ~0 of 131K pixels). setprio(1) around MFMA cluster (R9).
__device__ __forceinline__ void vq_chunk(
    int cc, bool dopf, const uint4* __restrict__ fragp, int l,
    uint4 (&bcur)[8], uint4 (&bnxt)[8],
    const bf16x8 (&a_hi)[4][2], const bf16x8 (&a_lo)[4][2],
    const float* __restrict__ nrm_lds,
    float (&best)[4][4], int (&bidx)[4][4]) {
    if (dopf) {
        const int ctb = (cc + 1) << 1;
#pragma unroll
        for (int i = 0; i < 8; ++i) {
            int ct = i >> 2, ks = (i >> 1) & 1, h = i & 1;
            bnxt[i] = fragp[(((ctb + ct) * 2 + ks) * 2 + h) * 64 + l];
        }
    }
    f32x4 accP[4][2], accQ[4][2];
    __builtin_amdgcn_s_setprio(1);
#pragma unroll
    for (int pt = 0; pt < 4; ++pt)
#pragma unroll
    for (int ct = 0; ct < 2; ++ct) {
        f32x4 p = {0.f, 0.f, 0.f, 0.f};
        f32x4 q = {0.f, 0.f, 0.f, 0.f};
#pragma unroll
        for (int ks = 0; ks < 2; ++ks) {
            bf16x8 bh = __builtin_bit_cast(bf16x8, bcur[ct * 4 + ks * 2 + 0]);
            bf16x8 bl = __builtin_bit_cast(bf16x8, bcur[ct * 4 + ks * 2 + 1]);
            p = __builtin_amdgcn_mfma_f32_16x16x32_bf16(a_hi[pt][ks], bh, p, 0, 0, 0);
            p = __builtin_amdgcn_mfma_f32_16x16x32_bf16(a_hi[pt][ks], bl, p, 0, 0, 0);
            q = __builtin_amdgcn_mfma_f32_16x16x32_bf16(a_lo[pt][ks], bh, q, 0, 0, 0);
            q = __builtin_amdgcn_mfma_f32_16x16x32_bf16(a_lo[pt][ks], bl, q, 0, 0, 0);
        }
        accP[pt][ct] = p; accQ[pt][ct] = q;
    }
    __builtin_amdgcn_s_setprio(0);
    // argmin update; C/D: col(code)=lane&15, row(pix)=(lane>>4)*4+reg
    const int cb = cc << 5;
#pragma unroll
    for (int ct = 0; ct < 2; ++ct) {
        int code = cb + ct * 16 + (l & 15);
        float nv = nrm_lds[code];
#pragma unroll
        for (int pt = 0; pt < 4; ++pt)
#pragma unroll
        for (int r = 0; r < 4; ++r) {
            float dot = accP[pt][ct][r] + accQ[pt][ct][r];
            float d = fmaf(-2.f, dot, nv);
            if (d < best[pt][r]) { best[pt][r] = d; bidx[pt][r] = code; }
        }
    }
}

// Main — R9 base (best: 52.5us main / 129.9 total), two ILP changes:
// (1) split accumulators in vq_chunk (above); (2) epilogue ping-pong tiles:
// two [64][65] tiles inside xs (pointer computed arithmetically per slice —
// R12's pointer-ARRAY initializer from an LDS object doesn't compile on
// gfx950), gather(s+1) overlaps scatter(s), barriers 8 -> 5, bit-exact.
// Occupancy axis closed (R11: 2048 waves / 256 CU = 8 waves/CU structural
// cap at 64px/wave). Tail = R0 ordering: relaxed atomics before epilogue
// (R6/R7: ordered agent-scope atomics cost 15-30us), zero-count bins skipped.
__global__ __launch_bounds__(256, 2) void vq_main(const float* __restrict__ in,
                                                  const float* __restrict__ emb,
                                                  float* __restrict__ out,
                                                  float* __restrict__ ws) {
    __shared__ __align__(16) float xs[256 * 68];  // x [pix][d] pad-68; reused as 2 q-tiles
    __shared__ float    x2_lds[256];
    __shared__ float    nrm_lds[KCODES];
    __shared__ int      idx_lds[256];
    __shared__ unsigned cnt_lds[KCODES];
    __shared__ float    red_tot;

    const int t = threadIdx.x;
    cnt_lds[t] = 0u; cnt_lds[t + 256] = 0u;
    if (t == 0) red_tot = 0.f;

    const int pix0 = blockIdx.x << 8;
    const int b    = pix0 >> 12;
    const int hwb  = pix0 & (HWSZ - 1);

    // Stage x (thread t = pixel t): coalesced global reads, b128 LDS writes.
    const float* inb = in + b * (DDIM * HWSZ) + hwb + t;
    float x2 = 0.f;
#pragma unroll
    for (int c = 0; c < DDIM; c += 4) {
        float4 v;
        v.x = inb[(c + 0) * HWSZ]; v.y = inb[(c + 1) * HWSZ];
        v.z = inb[(c + 2) * HWSZ]; v.w = inb[(c + 3) * HWSZ];
        *reinterpret_cast<float4*>(&xs[t * 68 + c]) = v;
        x2 = fmaf(v.x, v.x, x2); x2 = fmaf(v.y, v.y, x2);
        x2 = fmaf(v.z, v.z, x2); x2 = fmaf(v.w, v.w, x2);
    }
    x2_lds[t] = x2;
    nrm_lds[t]       = ws[WS_NRM_OFF + t];
    nrm_lds[t + 256] = ws[WS_NRM_OFF + t + 256];
    __syncthreads();

    const int l = t & 63, wid = t >> 6;   // wave handles pixels [wid*64, +64)

    // A-fragments (A[m][k]: m=lane&15, k=(lane>>4)*8+j), hi/lo bf16 split.
    bf16x8 a_hi[4][2], a_lo[4][2];
#pragma unroll
    for (int pt = 0; pt < 4; ++pt)
#pragma unroll
    for (int ks = 0; ks < 2; ++ks) {
        int pixl = wid * 64 + pt * 16 + (l & 15);
        int d0   = ks * 32 + ((l >> 4) & 3) * 8;
        const float4* p = reinterpret_cast<const float4*>(&xs[pixl * 68 + d0]);
        float4 f0 = p[0], f1 = p[1];
        float fv[8] = {f0.x, f0.y, f0.z, f0.w, f1.x, f1.y, f1.z, f1.w};
        bf16x8 h8, l8;
#pragma unroll
        for (int j = 0; j < 8; ++j) {
            __bf16 hb = (__bf16)fv[j];
            h8[j] = hb;
            l8[j] = (__bf16)(fv[j] - (float)hb);
        }
        a_hi[pt][ks] = h8; a_lo[pt][ks] = l8;
    }

    const uint4* fragp = reinterpret_cast<const uint4*>(ws + WS_FRAG_F32);
    float best[4][4]; int bidx[4][4];
#pragma unroll
    for (int pt = 0; pt < 4; ++pt)
#pragma unroll
    for (int r = 0; r < 4; ++r) { best[pt][r] = 3.4e38f; bidx[pt][r] = 0; }

    // B-frag ping-pong: b0/b1 alternate as cur/next each chunk; 8 frags/chunk
    // = [ct][ks][h]. Barrier-free: waves free-run, prefetch covers L2 latency.
    uint4 b0[8], b1[8];
#pragma unroll
    for (int i = 0; i < 8; ++i) {
        int ct = i >> 2, ks = (i >> 1) & 1, h = i & 1;
        b0[i] = fragp[(((ct) * 2 + ks) * 2 + h) * 64 + l];
    }

#pragma unroll 1
    for (int c = 0; c < 16; c += 2) {
        vq_chunk(c,     true,         fragp, l, b0, b1, a_hi, a_lo, nrm_lds, best, bidx);
        vq_chunk(c + 1, (c + 1) < 15, fragp, l, b1, b0, a_hi, a_lo, nrm_lds, best, bidx);
    }

    // Cross-lane argmin within each 16-lane group (codes spread over lane&15);
    // (dist, then idx) min = exact first-min semantics.
#pragma unroll
    for (int off = 1; off < 16; off <<= 1) {
#pragma unroll
        for (int pt = 0; pt < 4; ++pt)
#pragma unroll
        for (int r = 0; r < 4; ++r) {
            float ob = __shfl_xor(best[pt][r], off, 64);
            int   oi = __shfl_xor(bidx[pt][r], off, 64);
            bool take = (ob < best[pt][r]) || (ob == best[pt][r] && oi < bidx[pt][r]);
            if (take) { best[pt][r] = ob; bidx[pt][r] = oi; }
        }
    }
    if ((l & 15) == 0) {
        int q = l >> 4;
        float lp = 0.f;
#pragma unroll
        for (int pt = 0; pt < 4; ++pt)
#pragma unroll
        for (int r = 0; r < 4; ++r) {
            int pixl = wid * 64 + pt * 16 + q * 4 + r;
            idx_lds[pixl] = bidx[pt][r];
            atomicAdd(&cnt_lds[bidx[pt][r]], 1u);
            lp += x2_lds[pixl] + best[pt][r];   // |x-e|^2 = x^2 + (|e|^2 - 2x.e)
        }
        atomicAdd(&red_tot, lp);
    }
    __syncthreads();

    // Relaxed global atomics issued before the epilogue (R0 ordering): they
    // drain at the first epilogue barrier, overlapped with the gather phase.
    // Zero-count bins skipped (bit-exact; >=50% fewer atomics).
    if (t == 0) atomicAdd(ws, red_tot);
    unsigned* gcnt = reinterpret_cast<unsigned*>(ws) + WS_CNT_OFF;
    {
        unsigned cv0 = cnt_lds[t];       if (cv0) atomicAdd(gcnt + t, cv0);
        unsigned cv1 = cnt_lds[t + 256]; if (cv1) atomicAdd(gcnt + t + 256, cv1);
    }

    // Epilogue — ping-pong tiles: tile pointer = xs + (slice&1)*4160 (runtime
    // LDS pointer arithmetic; no pointer-array initializer). Slice s+1's
    // gather (emb2 reads + LDS writes to tile (s+1)&1) overlaps slice s's
    // scatter (LDS reads from tile s&1 + NCHW writes); one barrier per slice.
    // Values and addresses identical to R9 -> bit-exact outputs.
    float* out2 = out + OUT_NCHW_OFF;   // NCHW
    float* out3 = out + OUT_NHWC_OFF;   // NHWC flat (float2-aligned)
    const float2* emb2 = reinterpret_cast<const float2*>(emb);
    float2* out3_2 = reinterpret_cast<float2*>(out3);

#define GATHER(S)                                                              \
    {                                                                          \
        float* qt = xs + ((S) & 1) * (64 * 65);                                \
        _Pragma("unroll")                                                      \
        for (int it = 0; it < 8; ++it) {                                       \
            int fid = it * 256 + t;                                            \
            int pp  = fid >> 5;                                                \
            int c2  = fid & 31;                                                \
            int row = idx_lds[(S) * 64 + pp];                                  \
            float2 v = emb2[row * 32 + c2];                                    \
            out3_2[(size_t)(pix0 + (S) * 64 + pp) * 32 + c2] = v;              \
            qt[pp * 65 + c2 * 2 + 0] = v.x;                                    \
            qt[pp * 65 + c2 * 2 + 1] = v.y;                                    \
        }                                                                      \
    }
#define SCATTER(S)                                                             \
    {                                                                          \
        float* qt = xs + ((S) & 1) * (64 * 65);                                \
        _Pragma("unroll")                                                      \
        for (int it = 0; it < 16; ++it) {                                      \
            int did = it * 256 + t;                                            \
            int c   = did >> 6;                                                \
            int hwl = did & 63;                                                \
            out2[(size_t)(b * DDIM + c) * HWSZ + hwb + (S) * 64 + hwl] =       \
                qt[hwl * 65 + c];                                              \
        }                                                                      \
    }

    GATHER(0);
    __syncthreads();
#pragma unroll 1
    for (int s = 0; s < 4; ++s) {
        if (s < 3) GATHER(s + 1);
        SCATTER(s);
        __syncthreads();
    }
#undef GATHER
#undef SCATTER
}

__global__ __launch_bounds__(256) void vq_fin(float* __restrict__ out,
                                              const float* __restrict__ ws) {
    const unsigned* cnt = reinterpret_cast<const unsigned*>(ws) + WS_CNT_OFF;
    int t = threadIdx.x;  // 256
    double s = 0.0;
#pragma unroll
    for (int k = t; k < KCODES; k += 256) {
        double p = (double)cnt[k] / (double)NPIX;
        s += p * log(p + 1e-10);
    }
#pragma unroll
    for (int o = 32; o > 0; o >>= 1) s += __shfl_xor(s, o, 64);
    __shared__ double rd[4];
    if ((t & 63) == 0) rd[t >> 6] = s;
    __syncthreads();
    if (t == 0) {
        double tot = rd[0] + rd[1] + rd[2] + rd[3];
        out[OUT_PERP_IDX] = (float)exp(-tot);
        out[0] = 0.25f * ws[0] / (float)NELEM;
    }
}

extern "C" void kernel_launch(void* const* d_in, const int* in_sizes, int n_in,
                              void* d_out, int out_size, void* d_ws, size_t ws_size,
                              hipStream_t stream) {
    const float* in  = (const float*)d_in[0];
    const float* emb = (const float*)d_in[1];
    float* out = (float*)d_out;
    float* ws  = (float*)d_ws;

    // vq_prep zeroes loss+counts and overwrites norms + frag region:
    // no memset dispatch needed. Kernel boundaries provide cross-block
    // ordering (in-kernel tickets proven to cost 15-30us, R6/R7).
    vq_prep<<<32, 256, 0, stream>>>(emb, ws);
    vq_main<<<NBLOCKS, 256, 0, stream>>>(in, emb, out, ws);
    vq_fin<<<1, 256, 0, stream>>>(out, ws);
}

// Round 14
// 127.013 us; speedup vs baseline: 2.0329x; 1.0155x over previous
//
#include <hip/hip_runtime.h>
#include <math.h>

// Problem constants
#define NPIX   131072      // 32 * 64 * 64 pixels
#define KCODES 512
#define DDIM   64
#define HWSZ   4096        // 64*64
#define NELEM  8388608     // NPIX * DDIM

// d_out layout (fp32): [0]=loss, [1..1+NELEM)=q_nchw, [1+NELEM]=perplexity,
// [2+NELEM .. 2+2*NELEM)=q_nhwc flat
#define OUT_NCHW_OFF 1
#define OUT_PERP_IDX (1 + NELEM)
#define OUT_NHWC_OFF (2 + NELEM)

// ws layout (fp32 words): [0]=loss, [16..528)=|e|^2, [544..1056)=counts(uint),
// [2048..) = e bf16 hi/lo fragments in MFMA B-layout (byte 8192, 128KB)
#define WS_NRM_OFF  16
#define WS_CNT_OFF  544
#define WS_FRAG_F32 2048

#define NBLOCKS (NPIX / 256)   // 512 blocks, 256 pixels each (R9 geometry)

typedef __bf16 bf16x8 __attribute__((ext_vector_type(8)));
typedef float  f32x4  __attribute__((ext_vector_type(4)));

// Fused prep (memset + norms + pack in one dispatch; proven R2-R13). Thread
// tid = [ctile(32)][kstep(2)][h(2)][lane(64)] packs e into bf16 hi/lo MFMA
// B-fragments (16x16x32: B[k][n], n=lane&15, k=(lane>>4)*8+j); 16B coalesced.
// tid<512 computes |e|^2; tid in [512,1024) zeros counts; tid 0 zeros loss.
__global__ __launch_bounds__(256) void vq_prep(const float* __restrict__ emb,
                                               float* __restrict__ ws) {
    int tid  = blockIdx.x * 256 + threadIdx.x;   // 0..8191
    if (tid == 0) ws[0] = 0.f;
    if (tid < KCODES) {
        const float4* e4 = reinterpret_cast<const float4*>(emb + tid * DDIM);
        float s = 0.f;
#pragma unroll
        for (int i = 0; i < 16; ++i) {
            float4 v = e4[i];
            s = fmaf(v.x, v.x, s); s = fmaf(v.y, v.y, s);
            s = fmaf(v.z, v.z, s); s = fmaf(v.w, v.w, s);
        }
        ws[WS_NRM_OFF + tid] = s;
    } else if (tid < 2 * KCODES) {
        reinterpret_cast<unsigned*>(ws)[WS_CNT_OFF + (tid - KCODES)] = 0u;
    }

    int lane = tid & 63;
    int h    = (tid >> 6) & 1;
    int ks   = (tid >> 7) & 1;
    int ct   = tid >> 8;                         // 0..31
    int code = ct * 16 + (lane & 15);
    int d0   = ks * 32 + ((lane >> 4) & 3) * 8;
    const float* src = emb + code * DDIM + d0;
    unsigned short us[8];
#pragma unroll
    for (int j = 0; j < 8; ++j) {
        float f = src[j];
        __bf16 hb = (__bf16)f;                       // RTN
        if (h == 0) {
            us[j] = __builtin_bit_cast(unsigned short, hb);
        } else {
            __bf16 lb = (__bf16)(f - (float)hb);
            us[j] = __builtin_bit_cast(unsigned short, lb);
        }
    }
    uint4 v;
    v.x = us[0] | ((unsigned)us[1] << 16);
    v.y = us[2] | ((unsigned)us[3] << 16);
    v.z = us[4] | ((unsigned)us[5] << 16);
    v.w = us[6] | ((unsigned)us[7] << 16);
    reinterpret_cast<uint4*>(ws + WS_FRAG_F32)[tid] = v;
}

// One code-chunk (32 codes): optional prefetch of next chunk's B-frags into
// BNXT, then 48 MFMA — R14: THREE-TERM bf16 split. x.e = hi_x.hi_e +
// hi_x.lo_e + lo_x.hi_e (+ lo_x.lo_e DROPPED: bounded ~2^-18 relative,
// dot-contribution ~3e-5 typical — two orders below the fp32-split error the
// harness already tolerates at absmax 3.71875). 25% fewer MFMAs; R13 proved
// the loop is not dependency-bound, so the saving is pipe-work, not latency.
// setprio(1) around the MFMA cluster (R9). All indexing static.
__device__ __forceinline__ void vq_chunk(
    int cc, bool dopf, const uint4* __restrict__ fragp, int l,
    uint4 (&bcur)[8], uint4 (&bnxt)[8],
    const bf16x8 (&a_hi)[4][2], const bf16x8 (&a_lo)[4][2],
    const float* __restrict__ nrm_lds,
    float (&best)[4][4], int (&bidx)[4][4]) {
    if (dopf) {
        const int ctb = (cc + 1) << 1;
#pragma unroll
        for (int i = 0; i < 8; ++i) {
            int ct = i >> 2, ks = (i >> 1) & 1, h = i & 1;
            bnxt[i] = fragp[(((ctb + ct) * 2 + ks) * 2 + h) * 64 + l];
        }
    }
    f32x4 accP[4][2], accQ[4][2];
    __builtin_amdgcn_s_setprio(1);
#pragma unroll
    for (int pt = 0; pt < 4; ++pt)
#pragma unroll
    for (int ct = 0; ct < 2; ++ct) {
        f32x4 p = {0.f, 0.f, 0.f, 0.f};
        f32x4 q = {0.f, 0.f, 0.f, 0.f};
#pragma unroll
        for (int ks = 0; ks < 2; ++ks) {
            bf16x8 bh = __builtin_bit_cast(bf16x8, bcur[ct * 4 + ks * 2 + 0]);
            bf16x8 bl = __builtin_bit_cast(bf16x8, bcur[ct * 4 + ks * 2 + 1]);
            p = __builtin_amdgcn_mfma_f32_16x16x32_bf16(a_hi[pt][ks], bh, p, 0, 0, 0);
            p = __builtin_amdgcn_mfma_f32_16x16x32_bf16(a_hi[pt][ks], bl, p, 0, 0, 0);
            q = __builtin_amdgcn_mfma_f32_16x16x32_bf16(a_lo[pt][ks], bh, q, 0, 0, 0);
        }
        accP[pt][ct] = p; accQ[pt][ct] = q;
    }
    __builtin_amdgcn_s_setprio(0);
    // argmin update; C/D: col(code)=lane&15, row(pix)=(lane>>4)*4+reg
    const int cb = cc << 5;
#pragma unroll
    for (int ct = 0; ct < 2; ++ct) {
        int code = cb + ct * 16 + (l & 15);
        float nv = nrm_lds[code];
#pragma unroll
        for (int pt = 0; pt < 4; ++pt)
#pragma unroll
        for (int r = 0; r < 4; ++r) {
            float dot = accP[pt][ct][r] + accQ[pt][ct][r];
            float d = fmaf(-2.f, dot, nv);
            if (d < best[pt][r]) { best[pt][r] = d; bidx[pt][r] = code; }
        }
    }
}

// Main — R13 base (best: 53.5us main / 129.0 total); single work change:
// 3-term bf16 split in vq_chunk (above). Minor bit-exact tweak: chunk-0
// B-loads issued BEFORE the x-staging loop (independent of xs -> their L2
// latency hides under the 64 staging loads). All structural axes closed
// (R9-R13): occupancy grid-pinned at 8 waves/CU, ILP null, scheduling
// captured, B-source L2-optimal, tail = R0 relaxed-atomic ordering.
__global__ __launch_bounds__(256, 2) void vq_main(const float* __restrict__ in,
                                                  const float* __restrict__ emb,
                                                  float* __restrict__ out,
                                                  float* __restrict__ ws) {
    __shared__ __align__(16) float xs[256 * 68];  // x [pix][d] pad-68; reused as 2 q-tiles
    __shared__ float    x2_lds[256];
    __shared__ float    nrm_lds[KCODES];
    __shared__ int      idx_lds[256];
    __shared__ unsigned cnt_lds[KCODES];
    __shared__ float    red_tot;

    const int t = threadIdx.x;
    const int l = t & 63, wid = t >> 6;   // wave handles pixels [wid*64, +64)
    cnt_lds[t] = 0u; cnt_lds[t + 256] = 0u;
    if (t == 0) red_tot = 0.f;

    const int pix0 = blockIdx.x << 8;
    const int b    = pix0 >> 12;
    const int hwb  = pix0 & (HWSZ - 1);

    // Chunk-0 B-frags issued first: independent of xs, latency hides under
    // the staging loads below (bit-exact; values identical).
    const uint4* fragp = reinterpret_cast<const uint4*>(ws + WS_FRAG_F32);
    uint4 b0[8], b1[8];
#pragma unroll
    for (int i = 0; i < 8; ++i) {
        int ct = i >> 2, ks = (i >> 1) & 1, h = i & 1;
        b0[i] = fragp[(((ct) * 2 + ks) * 2 + h) * 64 + l];
    }

    // Stage x (thread t = pixel t): coalesced global reads, b128 LDS writes.
    const float* inb = in + b * (DDIM * HWSZ) + hwb + t;
    float x2 = 0.f;
#pragma unroll
    for (int c = 0; c < DDIM; c += 4) {
        float4 v;
        v.x = inb[(c + 0) * HWSZ]; v.y = inb[(c + 1) * HWSZ];
        v.z = inb[(c + 2) * HWSZ]; v.w = inb[(c + 3) * HWSZ];
        *reinterpret_cast<float4*>(&xs[t * 68 + c]) = v;
        x2 = fmaf(v.x, v.x, x2); x2 = fmaf(v.y, v.y, x2);
        x2 = fmaf(v.z, v.z, x2); x2 = fmaf(v.w, v.w, x2);
    }
    x2_lds[t] = x2;
    nrm_lds[t]       = ws[WS_NRM_OFF + t];
    nrm_lds[t + 256] = ws[WS_NRM_OFF + t + 256];
    __syncthreads();

    // A-fragments (A[m][k]: m=lane&15, k=(lane>>4)*8+j), hi/lo bf16 split.
    bf16x8 a_hi[4][2], a_lo[4][2];
#pragma unroll
    for (int pt = 0; pt < 4; ++pt)
#pragma unroll
    for (int ks = 0; ks < 2; ++ks) {
        int pixl = wid * 64 + pt * 16 + (l & 15);
        int d0   = ks * 32 + ((l >> 4) & 3) * 8;
        const float4* p = reinterpret_cast<const float4*>(&xs[pixl * 68 + d0]);
        float4 f0 = p[0], f1 = p[1];
        float fv[8] = {f0.x, f0.y, f0.z, f0.w, f1.x, f1.y, f1.z, f1.w};
        bf16x8 h8, l8;
#pragma unroll
        for (int j = 0; j < 8; ++j) {
            __bf16 hb = (__bf16)fv[j];
            h8[j] = hb;
            l8[j] = (__bf16)(fv[j] - (float)hb);
        }
        a_hi[pt][ks] = h8; a_lo[pt][ks] = l8;
    }

    float best[4][4]; int bidx[4][4];
#pragma unroll
    for (int pt = 0; pt < 4; ++pt)
#pragma unroll
    for (int r = 0; r < 4; ++r) { best[pt][r] = 3.4e38f; bidx[pt][r] = 0; }

#pragma unroll 1
    for (int c = 0; c < 16; c += 2) {
        vq_chunk(c,     true,         fragp, l, b0, b1, a_hi, a_lo, nrm_lds, best, bidx);
        vq_chunk(c + 1, (c + 1) < 15, fragp, l, b1, b0, a_hi, a_lo, nrm_lds, best, bidx);
    }

    // Cross-lane argmin within each 16-lane group (codes spread over lane&15);
    // (dist, then idx) min = exact first-min semantics.
#pragma unroll
    for (int off = 1; off < 16; off <<= 1) {
#pragma unroll
        for (int pt = 0; pt < 4; ++pt)
#pragma unroll
        for (int r = 0; r < 4; ++r) {
            float ob = __shfl_xor(best[pt][r], off, 64);
            int   oi = __shfl_xor(bidx[pt][r], off, 64);
            bool take = (ob < best[pt][r]) || (ob == best[pt][r] && oi < bidx[pt][r]);
            if (take) { best[pt][r] = ob; bidx[pt][r] = oi; }
        }
    }
    if ((l & 15) == 0) {
        int q = l >> 4;
        float lp = 0.f;
#pragma unroll
        for (int pt = 0; pt < 4; ++pt)
#pragma unroll
        for (int r = 0; r < 4; ++r) {
            int pixl = wid * 64 + pt * 16 + q * 4 + r;
            idx_lds[pixl] = bidx[pt][r];
            atomicAdd(&cnt_lds[bidx[pt][r]], 1u);
            lp += x2_lds[pixl] + best[pt][r];   // |x-e|^2 = x^2 + (|e|^2 - 2x.e)
        }
        atomicAdd(&red_tot, lp);
    }
    __syncthreads();

    // Relaxed global atomics issued before the epilogue (R0 ordering): they
    // drain at the first epilogue barrier, overlapped with the gather phase.
    // Zero-count bins skipped (bit-exact; >=50% fewer atomics).
    if (t == 0) atomicAdd(ws, red_tot);
    unsigned* gcnt = reinterpret_cast<unsigned*>(ws) + WS_CNT_OFF;
    {
        unsigned cv0 = cnt_lds[t];       if (cv0) atomicAdd(gcnt + t, cv0);
        unsigned cv1 = cnt_lds[t + 256]; if (cv1) atomicAdd(gcnt + t + 256, cv1);
    }

    // Epilogue — ping-pong tiles (R13-proven): tile ptr = xs + (s&1)*4160;
    // gather(s+1) overlaps scatter(s); one barrier per slice; bit-exact.
    float* out2 = out + OUT_NCHW_OFF;   // NCHW
    float* out3 = out + OUT_NHWC_OFF;   // NHWC flat (float2-aligned)
    const float2* emb2 = reinterpret_cast<const float2*>(emb);
    float2* out3_2 = reinterpret_cast<float2*>(out3);

#define GATHER(S)                                                              \
    {                                                                          \
        float* qt = xs + ((S) & 1) * (64 * 65);                                \
        _Pragma("unroll")                                                      \
        for (int it = 0; it < 8; ++it) {                                       \
            int fid = it * 256 + t;                                            \
            int pp  = fid >> 5;                                                \
            int c2  = fid & 31;                                                \
            int row = idx_lds[(S) * 64 + pp];                                  \
            float2 v = emb2[row * 32 + c2];                                    \
            out3_2[(size_t)(pix0 + (S) * 64 + pp) * 32 + c2] = v;              \
            qt[pp * 65 + c2 * 2 + 0] = v.x;                                    \
            qt[pp * 65 + c2 * 2 + 1] = v.y;                                    \
        }                                                                      \
    }
#define SCATTER(S)                                                             \
    {                                                                          \
        float* qt = xs + ((S) & 1) * (64 * 65);                                \
        _Pragma("unroll")                                                      \
        for (int it = 0; it < 16; ++it) {                                      \
            int did = it * 256 + t;                                            \
            int c   = did >> 6;                                                \
            int hwl = did & 63;                                                \
            out2[(size_t)(b * DDIM + c) * HWSZ + hwb + (S) * 64 + hwl] =       \
                qt[hwl * 65 + c];                                              \
        }                                                                      \
    }

    GATHER(0);
    __syncthreads();
#pragma unroll 1
    for (int s = 0; s < 4; ++s) {
        if (s < 3) GATHER(s + 1);
        SCATTER(s);
        __syncthreads();
    }
#undef GATHER
#undef SCATTER
}

__global__ __launch_bounds__(256) void vq_fin(float* __restrict__ out,
                                              const float* __restrict__ ws) {
    const unsigned* cnt = reinterpret_cast<const unsigned*>(ws) + WS_CNT_OFF;
    int t = threadIdx.x;  // 256
    double s = 0.0;
#pragma unroll
    for (int k = t; k < KCODES; k += 256) {
        double p = (double)cnt[k] / (double)NPIX;
        s += p * log(p + 1e-10);
    }
#pragma unroll
    for (int o = 32; o > 0; o >>= 1) s += __shfl_xor(s, o, 64);
    __shared__ double rd[4];
    if ((t & 63) == 0) rd[t >> 6] = s;
    __syncthreads();
    if (t == 0) {
        double tot = rd[0] + rd[1] + rd[2] + rd[3];
        out[OUT_PERP_IDX] = (float)exp(-tot);
        out[0] = 0.25f * ws[0] / (float)NELEM;
    }
}

extern "C" void kernel_launch(void* const* d_in, const int* in_sizes, int n_in,
                              void* d_out, int out_size, void* d_ws, size_t ws_size,
                              hipStream_t stream) {
    const float* in  = (const float*)d_in[0];
    const float* emb = (const float*)d_in[1];
    float* out = (float*)d_out;
    float* ws  = (float*)d_ws;

    // vq_prep zeroes loss+counts and overwrites norms + frag region:
    // no memset dispatch needed. Kernel boundaries provide cross-block
    // ordering (in-kernel tickets proven to cost 15-30us, R6/R7).
    vq_prep<<<32, 256, 0, stream>>>(emb, ws);
    vq_main<<<NBLOCKS, 256, 0, stream>>>(in, emb, out, ws);
    vq_fin<<<1, 256, 0, stream>>>(out, ws);
}

// Round 15
// 126.199 us; speedup vs baseline: 2.0460x; 1.0065x over previous
//
#include <hip/hip_runtime.h>
#include <math.h>

// Problem constants
#define NPIX   131072      // 32 * 64 * 64 pixels
#define KCODES 512
#define DDIM   64
#define HWSZ   4096        // 64*64
#define NELEM  8388608     // NPIX * DDIM

// d_out layout (fp32): [0]=loss, [1..1+NELEM)=q_nchw, [1+NELEM]=perplexity,
// [2+NELEM .. 2+2*NELEM)=q_nhwc flat
#define OUT_NCHW_OFF 1
#define OUT_PERP_IDX (1 + NELEM)
#define OUT_NHWC_OFF (2 + NELEM)

// ws layout (fp32 words): [0]=loss, [16..528)=|e|^2, [544..1056)=counts(uint),
// [2048..) = e bf16 hi/lo fragments in MFMA B-layout (byte 8192, 128KB)
#define WS_NRM_OFF  16
#define WS_CNT_OFF  544
#define WS_FRAG_F32 2048

#define NBLOCKS (NPIX / 256)   // 512 blocks, 256 pixels each (R9 geometry)

typedef __bf16 bf16x8 __attribute__((ext_vector_type(8)));
typedef float  f32x4  __attribute__((ext_vector_type(4)));

// Fused prep (memset + norms + pack in one dispatch; proven R2-R14). Thread
// tid = [ctile(32)][kstep(2)][h(2)][lane(64)] packs e into bf16 hi/lo MFMA
// B-fragments (16x16x32: B[k][n], n=lane&15, k=(lane>>4)*8+j); 16B coalesced.
// tid<512 computes |e|^2; tid in [512,1024) zeros counts; tid 0 zeros loss.
__global__ __launch_bounds__(256) void vq_prep(const float* __restrict__ emb,
                                               float* __restrict__ ws) {
    int tid  = blockIdx.x * 256 + threadIdx.x;   // 0..8191
    if (tid == 0) ws[0] = 0.f;
    if (tid < KCODES) {
        const float4* e4 = reinterpret_cast<const float4*>(emb + tid * DDIM);
        float s = 0.f;
#pragma unroll
        for (int i = 0; i < 16; ++i) {
            float4 v = e4[i];
            s = fmaf(v.x, v.x, s); s = fmaf(v.y, v.y, s);
            s = fmaf(v.z, v.z, s); s = fmaf(v.w, v.w, s);
        }
        ws[WS_NRM_OFF + tid] = s;
    } else if (tid < 2 * KCODES) {
        reinterpret_cast<unsigned*>(ws)[WS_CNT_OFF + (tid - KCODES)] = 0u;
    }

    int lane = tid & 63;
    int h    = (tid >> 6) & 1;
    int ks   = (tid >> 7) & 1;
    int ct   = tid >> 8;                         // 0..31
    int code = ct * 16 + (lane & 15);
    int d0   = ks * 32 + ((lane >> 4) & 3) * 8;
    const float* src = emb + code * DDIM + d0;
    unsigned short us[8];
#pragma unroll
    for (int j = 0; j < 8; ++j) {
        float f = src[j];
        __bf16 hb = (__bf16)f;                       // RTN
        if (h == 0) {
            us[j] = __builtin_bit_cast(unsigned short, hb);
        } else {
            __bf16 lb = (__bf16)(f - (float)hb);
            us[j] = __builtin_bit_cast(unsigned short, lb);
        }
    }
    uint4 v;
    v.x = us[0] | ((unsigned)us[1] << 16);
    v.y = us[2] | ((unsigned)us[3] << 16);
    v.z = us[4] | ((unsigned)us[5] << 16);
    v.w = us[6] | ((unsigned)us[7] << 16);
    reinterpret_cast<uint4*>(ws + WS_FRAG_F32)[tid] = v;
}

// One code-chunk (32 codes): optional prefetch of next chunk's B-frags into
// BNXT, then 48 MFMA — 3-term bf16 split (R14-proven, absmax unchanged):
// x.e = hi.hi + hi.lo + lo.hi, now accumulated in a SINGLE chain per C-tile
// (R15: R13 proved depth is not the limiter, so merging accQ into accP
// removes 16 vector adds/chunk + 16 VGPRs for free; ~1-ulp regroup, same
// risk class as R13/R14 which kept absmax at 3.71875).
// setprio(1) around the MFMA cluster (R9). All indexing static.
__device__ __forceinline__ void vq_chunk(
    int cc, bool dopf, const uint4* __restrict__ fragp, int l,
    uint4 (&bcur)[8], uint4 (&bnxt)[8],
    const bf16x8 (&a_hi)[4][2], const bf16x8 (&a_lo)[4][2],
    const float* __restrict__ nrm_lds,
    float (&best)[4][4], int (&bidx)[4][4]) {
    if (dopf) {
        const int ctb = (cc + 1) << 1;
#pragma unroll
        for (int i = 0; i < 8; ++i) {
            int ct = i >> 2, ks = (i >> 1) & 1, h = i & 1;
            bnxt[i] = fragp[(((ctb + ct) * 2 + ks) * 2 + h) * 64 + l];
        }
    }
    f32x4 acc[4][2];
    __builtin_amdgcn_s_setprio(1);
#pragma unroll
    for (int pt = 0; pt < 4; ++pt)
#pragma unroll
    for (int ct = 0; ct < 2; ++ct) {
        f32x4 p = {0.f, 0.f, 0.f, 0.f};
#pragma unroll
        for (int ks = 0; ks < 2; ++ks) {
            bf16x8 bh = __builtin_bit_cast(bf16x8, bcur[ct * 4 + ks * 2 + 0]);
            bf16x8 bl = __builtin_bit_cast(bf16x8, bcur[ct * 4 + ks * 2 + 1]);
            p = __builtin_amdgcn_mfma_f32_16x16x32_bf16(a_hi[pt][ks], bh, p, 0, 0, 0);
            p = __builtin_amdgcn_mfma_f32_16x16x32_bf16(a_hi[pt][ks], bl, p, 0, 0, 0);
            p = __builtin_amdgcn_mfma_f32_16x16x32_bf16(a_lo[pt][ks], bh, p, 0, 0, 0);
        }
        acc[pt][ct] = p;
    }
    __builtin_amdgcn_s_setprio(0);
    // argmin update; C/D: col(code)=lane&15, row(pix)=(lane>>4)*4+reg
    const int cb = cc << 5;
#pragma unroll
    for (int ct = 0; ct < 2; ++ct) {
        int code = cb + ct * 16 + (l & 15);
        float nv = nrm_lds[code];
#pragma unroll
        for (int pt = 0; pt < 4; ++pt)
#pragma unroll
        for (int r = 0; r < 4; ++r) {
            float d = fmaf(-2.f, acc[pt][ct][r], nv);
            if (d < best[pt][r]) { best[pt][r] = d; bidx[pt][r] = code; }
        }
    }
}

// Main — R14 base (best: ~51us main / 127.0 total); R15 changes:
// (1) BARRIER RESTRUCTURE: staging is wave-local (thread t = pixel t; wave
//     wid writes AND reads exactly pixels [wid*64,+64) of xs/x2_lds), so the
//     shared-init (nrm loads, cnt zero, red_tot) moves to the top with one
//     cheap barrier while ~nothing is in flight; the staging -> A-convert ->
//     chunk pipeline then runs BARRIER-FREE per wave — wave 3's staging-tail
//     latency overlaps wave 0's MFMAs instead of draining at a block-wide
//     vmcnt(0). Bit-exact (same values, same per-wave op sequence).
// (2) single-chain 3-term accumulation in vq_chunk (above).
// All other axes closed R9-R14. Tail = R0 relaxed-atomic ordering.
__global__ __launch_bounds__(256, 2) void vq_main(const float* __restrict__ in,
                                                  const float* __restrict__ emb,
                                                  float* __restrict__ out,
                                                  float* __restrict__ ws) {
    __shared__ __align__(16) float xs[256 * 68];  // x [pix][d] pad-68; reused as 2 q-tiles
    __shared__ float    x2_lds[256];
    __shared__ float    nrm_lds[KCODES];
    __shared__ int      idx_lds[256];
    __shared__ unsigned cnt_lds[KCODES];
    __shared__ float    red_tot;

    const int t = threadIdx.x;
    const int l = t & 63, wid = t >> 6;   // wave handles pixels [wid*64, +64)

    const int pix0 = blockIdx.x << 8;
    const int b    = pix0 >> 12;
    const int hwb  = pix0 & (HWSZ - 1);

    // Shared init FIRST: cnt zero + red_tot + norms; one cheap barrier with
    // only 2 loads/thread in flight. Everything after is wave-local until
    // the post-argmin reduce.
    cnt_lds[t] = 0u; cnt_lds[t + 256] = 0u;
    if (t == 0) red_tot = 0.f;
    nrm_lds[t]       = ws[WS_NRM_OFF + t];
    nrm_lds[t + 256] = ws[WS_NRM_OFF + t + 256];
    __syncthreads();

    // Chunk-0 B-frags issued next: their L2 latency hides under the 64
    // staging loads below (R14-proven placement, bit-exact).
    const uint4* fragp = reinterpret_cast<const uint4*>(ws + WS_FRAG_F32);
    uint4 b0[8], b1[8];
#pragma unroll
    for (int i = 0; i < 8; ++i) {
        int ct = i >> 2, ks = (i >> 1) & 1, h = i & 1;
        b0[i] = fragp[(((ct) * 2 + ks) * 2 + h) * 64 + l];
    }

    // Stage x (thread t = pixel t): coalesced global reads, b128 LDS writes.
    // Wave-local: no barrier needed before consuming xs (intra-wave lgkmcnt
    // ordering is compiler-handled).
    const float* inb = in + b * (DDIM * HWSZ) + hwb + t;
    float x2 = 0.f;
#pragma unroll
    for (int c = 0; c < DDIM; c += 4) {
        float4 v;
        v.x = inb[(c + 0) * HWSZ]; v.y = inb[(c + 1) * HWSZ];
        v.z = inb[(c + 2) * HWSZ]; v.w = inb[(c + 3) * HWSZ];
        *reinterpret_cast<float4*>(&xs[t * 68 + c]) = v;
        x2 = fmaf(v.x, v.x, x2); x2 = fmaf(v.y, v.y, x2);
        x2 = fmaf(v.z, v.z, x2); x2 = fmaf(v.w, v.w, x2);
    }
    x2_lds[t] = x2;

    // A-fragments (A[m][k]: m=lane&15, k=(lane>>4)*8+j), hi/lo bf16 split.
    bf16x8 a_hi[4][2], a_lo[4][2];
#pragma unroll
    for (int pt = 0; pt < 4; ++pt)
#pragma unroll
    for (int ks = 0; ks < 2; ++ks) {
        int pixl = wid * 64 + pt * 16 + (l & 15);
        int d0   = ks * 32 + ((l >> 4) & 3) * 8;
        const float4* p = reinterpret_cast<const float4*>(&xs[pixl * 68 + d0]);
        float4 f0 = p[0], f1 = p[1];
        float fv[8] = {f0.x, f0.y, f0.z, f0.w, f1.x, f1.y, f1.z, f1.w};
        bf16x8 h8, l8;
#pragma unroll
        for (int j = 0; j < 8; ++j) {
            __bf16 hb = (__bf16)fv[j];
            h8[j] = hb;
            l8[j] = (__bf16)(fv[j] - (float)hb);
        }
        a_hi[pt][ks] = h8; a_lo[pt][ks] = l8;
    }

    float best[4][4]; int bidx[4][4];
#pragma unroll
    for (int pt = 0; pt < 4; ++pt)
#pragma unroll
    for (int r = 0; r < 4; ++r) { best[pt][r] = 3.4e38f; bidx[pt][r] = 0; }

#pragma unroll 1
    for (int c = 0; c < 16; c += 2) {
        vq_chunk(c,     true,         fragp, l, b0, b1, a_hi, a_lo, nrm_lds, best, bidx);
        vq_chunk(c + 1, (c + 1) < 15, fragp, l, b1, b0, a_hi, a_lo, nrm_lds, best, bidx);
    }

    // Cross-lane argmin within each 16-lane group (codes spread over lane&15);
    // (dist, then idx) min = exact first-min semantics.
#pragma unroll
    for (int off = 1; off < 16; off <<= 1) {
#pragma unroll
        for (int pt = 0; pt < 4; ++pt)
#pragma unroll
        for (int r = 0; r < 4; ++r) {
            float ob = __shfl_xor(best[pt][r], off, 64);
            int   oi = __shfl_xor(bidx[pt][r], off, 64);
            bool take = (ob < best[pt][r]) || (ob == best[pt][r] && oi < bidx[pt][r]);
            if (take) { best[pt][r] = ob; bidx[pt][r] = oi; }
        }
    }
    if ((l & 15) == 0) {
        int q = l >> 4;
        float lp = 0.f;
#pragma unroll
        for (int pt = 0; pt < 4; ++pt)
#pragma unroll
        for (int r = 0; r < 4; ++r) {
            int pixl = wid * 64 + pt * 16 + q * 4 + r;
            idx_lds[pixl] = bidx[pt][r];
            atomicAdd(&cnt_lds[bidx[pt][r]], 1u);
            lp += x2_lds[pixl] + best[pt][r];   // |x-e|^2 = x^2 + (|e|^2 - 2x.e)
        }
        atomicAdd(&red_tot, lp);
    }
    __syncthreads();

    // Relaxed global atomics issued before the epilogue (R0 ordering): they
    // drain at the first epilogue barrier, overlapped with the gather phase.
    // Zero-count bins skipped (bit-exact; >=50% fewer atomics).
    if (t == 0) atomicAdd(ws, red_tot);
    unsigned* gcnt = reinterpret_cast<unsigned*>(ws) + WS_CNT_OFF;
    {
        unsigned cv0 = cnt_lds[t];       if (cv0) atomicAdd(gcnt + t, cv0);
        unsigned cv1 = cnt_lds[t + 256]; if (cv1) atomicAdd(gcnt + t + 256, cv1);
    }

    // Epilogue — ping-pong tiles (R13/R14-proven): tile ptr = xs + (s&1)*4160;
    // gather(s+1) overlaps scatter(s); one barrier per slice; bit-exact.
    float* out2 = out + OUT_NCHW_OFF;   // NCHW
    float* out3 = out + OUT_NHWC_OFF;   // NHWC flat (float2-aligned)
    const float2* emb2 = reinterpret_cast<const float2*>(emb);
    float2* out3_2 = reinterpret_cast<float2*>(out3);

#define GATHER(S)                                                              \
    {                                                                          \
        float* qt = xs + ((S) & 1) * (64 * 65);                                \
        _Pragma("unroll")                                                      \
        for (int it = 0; it < 8; ++it) {                                       \
            int fid = it * 256 + t;                                            \
            int pp  = fid >> 5;                                                \
            int c2  = fid & 31;                                                \
            int row = idx_lds[(S) * 64 + pp];                                  \
            float2 v = emb2[row * 32 + c2];                                    \
            out3_2[(size_t)(pix0 + (S) * 64 + pp) * 32 + c2] = v;              \
            qt[pp * 65 + c2 * 2 + 0] = v.x;                                    \
            qt[pp * 65 + c2 * 2 + 1] = v.y;                                    \
        }                                                                      \
    }
#define SCATTER(S)                                                             \
    {                                                                          \
        float* qt = xs + ((S) & 1) * (64 * 65);                                \
        _Pragma("unroll")                                                      \
        for (int it = 0; it < 16; ++it) {                                      \
            int did = it * 256 + t;                                            \
            int c   = did >> 6;                                                \
            int hwl = did & 63;                                                \
            out2[(size_t)(b * DDIM + c) * HWSZ + hwb + (S) * 64 + hwl] =       \
                qt[hwl * 65 + c];                                              \
        }                                                                      \
    }

    GATHER(0);
    __syncthreads();
#pragma unroll 1
    for (int s = 0; s < 4; ++s) {
        if (s < 3) GATHER(s + 1);
        SCATTER(s);
        __syncthreads();
    }
#undef GATHER
#undef SCATTER
}

__global__ __launch_bounds__(256) void vq_fin(float* __restrict__ out,
                                              const float* __restrict__ ws) {
    const unsigned* cnt = reinterpret_cast<const unsigned*>(ws) + WS_CNT_OFF;
    int t = threadIdx.x;  // 256
    double s = 0.0;
#pragma unroll
    for (int k = t; k < KCODES; k += 256) {
        double p = (double)cnt[k] / (double)NPIX;
        s += p * log(p + 1e-10);
    }
#pragma unroll
    for (int o = 32; o > 0; o >>= 1) s += __shfl_xor(s, o, 64);
    __shared__ double rd[4];
    if ((t & 63) == 0) rd[t >> 6] = s;
    __syncthreads();
    if (t == 0) {
        double tot = rd[0] + rd[1] + rd[2] + rd[3];
        out[OUT_PERP_IDX] = (float)exp(-tot);
        out[0] = 0.25f * ws[0] / (float)NELEM;
    }
}

extern "C" void kernel_launch(void* const* d_in, const int* in_sizes, int n_in,
                              void* d_out, int out_size, void* d_ws, size_t ws_size,
                              hipStream_t stream) {
    const float* in  = (const float*)d_in[0];
    const float* emb = (const float*)d_in[1];
    float* out = (float*)d_out;
    float* ws  = (float*)d_ws;

    // vq_prep zeroes loss+counts and overwrites norms + frag region:
    // no memset dispatch needed. Kernel boundaries provide cross-block
    // ordering (in-kernel tickets proven to cost 15-30us, R6/R7).
    vq_prep<<<32, 256, 0, stream>>>(emb, ws);
    vq_main<<<NBLOCKS, 256, 0, stream>>>(in, emb, out, ws);
    vq_fin<<<1, 256, 0, stream>>>(out, ws);
}

// Round 17
// 124.111 us; speedup vs baseline: 2.0804x; 1.0168x over previous
//
#include <hip/hip_runtime.h>
#include <math.h>

// Problem constants
#define NPIX   131072      // 32 * 64 * 64 pixels
#define KCODES 512
#define DDIM   64
#define HWSZ   4096        // 64*64
#define NELEM  8388608     // NPIX * DDIM

// d_out layout (fp32): [0]=loss, [1..1+NELEM)=q_nchw, [1+NELEM]=perplexity,
// [2+NELEM .. 2+2*NELEM)=q_nhwc flat
#define OUT_NCHW_OFF 1
#define OUT_PERP_IDX (1 + NELEM)
#define OUT_NHWC_OFF (2 + NELEM)

// ws layout (fp32 words): [0]=loss, [16..528)=|e|^2, [544..1056)=counts(uint),
// [2048..) = e bf16 hi/lo fragments in MFMA B-layout (byte 8192, 128KB)
#define WS_NRM_OFF  16
#define WS_CNT_OFF  544
#define WS_FRAG_F32 2048

#define NBLOCKS (NPIX / 256)   // 512 blocks, 256 pixels each

typedef __bf16 bf16x8 __attribute__((ext_vector_type(8)));
typedef float  f32x4  __attribute__((ext_vector_type(4)));

// Fused prep (memset + norms + pack in one dispatch; proven R2-R15). Thread
// tid = [ctile(32)][kstep(2)][h(2)][lane(64)] packs e into bf16 hi/lo MFMA
// B-fragments (16x16x32: B[k][n], n=lane&15, k=(lane>>4)*8+j); 16B coalesced.
// tid<512 computes |e|^2; tid in [512,1024) zeros counts; tid 0 zeros loss.
__global__ __launch_bounds__(256) void vq_prep(const float* __restrict__ emb,
                                               float* __restrict__ ws) {
    int tid  = blockIdx.x * 256 + threadIdx.x;   // 0..8191
    if (tid == 0) ws[0] = 0.f;
    if (tid < KCODES) {
        const float4* e4 = reinterpret_cast<const float4*>(emb + tid * DDIM);
        float s = 0.f;
#pragma unroll
        for (int i = 0; i < 16; ++i) {
            float4 v = e4[i];
            s = fmaf(v.x, v.x, s); s = fmaf(v.y, v.y, s);
            s = fmaf(v.z, v.z, s); s = fmaf(v.w, v.w, s);
        }
        ws[WS_NRM_OFF + tid] = s;
    } else if (tid < 2 * KCODES) {
        reinterpret_cast<unsigned*>(ws)[WS_CNT_OFF + (tid - KCODES)] = 0u;
    }

    int lane = tid & 63;
    int h    = (tid >> 6) & 1;
    int ks   = (tid >> 7) & 1;
    int ct   = tid >> 8;                         // 0..31
    int code = ct * 16 + (lane & 15);
    int d0   = ks * 32 + ((lane >> 4) & 3) * 8;
    const float* src = emb + code * DDIM + d0;
    unsigned short us[8];
#pragma unroll
    for (int j = 0; j < 8; ++j) {
        float f = src[j];
        __bf16 hb = (__bf16)f;                       // RTN
        if (h == 0) {
            us[j] = __builtin_bit_cast(unsigned short, hb);
        } else {
            __bf16 lb = (__bf16)(f - (float)hb);
            us[j] = __builtin_bit_cast(unsigned short, lb);
        }
    }
    uint4 v;
    v.x = us[0] | ((unsigned)us[1] << 16);
    v.y = us[2] | ((unsigned)us[3] << 16);
    v.z = us[4] | ((unsigned)us[5] << 16);
    v.w = us[6] | ((unsigned)us[7] << 16);
    reinterpret_cast<uint4*>(ws + WS_FRAG_F32)[tid] = v;
}

// One code-chunk (32 codes): optional prefetch of next chunk's B-frags into
// BNXT, then 48 MFMA — 3-term bf16 split, single accumulation chain
// (R14/R15-proven, absmax unchanged): x.e = hi.hi + hi.lo + lo.hi
// (lo.lo dropped: ~2^-18 relative, two orders below accepted tolerance).
// setprio(1) around the MFMA cluster (R9). All indexing static.
__device__ __forceinline__ void vq_chunk(
    int cc, bool dopf, const uint4* __restrict__ fragp, int l,
    uint4 (&bcur)[8], uint4 (&bnxt)[8],
    const bf16x8 (&a_hi)[4][2], const bf16x8 (&a_lo)[4][2],
    const float* __restrict__ nrm_lds,
    float (&best)[4][4], int (&bidx)[4][4]) {
    if (dopf) {
        const int ctb = (cc + 1) << 1;
#pragma unroll
        for (int i = 0; i < 8; ++i) {
            int ct = i >> 2, ks = (i >> 1) & 1, h = i & 1;
            bnxt[i] = fragp[(((ctb + ct) * 2 + ks) * 2 + h) * 64 + l];
        }
    }
    f32x4 acc[4][2];
    __builtin_amdgcn_s_setprio(1);
#pragma unroll
    for (int pt = 0; pt < 4; ++pt)
#pragma unroll
    for (int ct = 0; ct < 2; ++ct) {
        f32x4 p = {0.f, 0.f, 0.f, 0.f};
#pragma unroll
        for (int ks = 0; ks < 2; ++ks) {
            bf16x8 bh = __builtin_bit_cast(bf16x8, bcur[ct * 4 + ks * 2 + 0]);
            bf16x8 bl = __builtin_bit_cast(bf16x8, bcur[ct * 4 + ks * 2 + 1]);
            p = __builtin_amdgcn_mfma_f32_16x16x32_bf16(a_hi[pt][ks], bh, p, 0, 0, 0);
            p = __builtin_amdgcn_mfma_f32_16x16x32_bf16(a_hi[pt][ks], bl, p, 0, 0, 0);
            p = __builtin_amdgcn_mfma_f32_16x16x32_bf16(a_lo[pt][ks], bh, p, 0, 0, 0);
        }
        acc[pt][ct] = p;
    }
    __builtin_amdgcn_s_setprio(0);
    // argmin update; C/D: col(code)=lane&15, row(pix)=(lane>>4)*4+reg
    const int cb = cc << 5;
#pragma unroll
    for (int ct = 0; ct < 2; ++ct) {
        int code = cb + ct * 16 + (l & 15);
        float nv = nrm_lds[code];
#pragma unroll
        for (int pt = 0; pt < 4; ++pt)
#pragma unroll
        for (int r = 0; r < 4; ++r) {
            float d = fmaf(-2.f, acc[pt][ct][r], nv);
            if (d < best[pt][r]) { best[pt][r] = d; bidx[pt][r] = code; }
        }
    }
}

// Main — R15 proven kernel (best: ~48.5us main / 126.2 total), restored
// token-identical. R16 lesson (final): cooperative single-dispatch fusion
// FAILS correctness on gfx950 — grid.sync() arrival does not make other
// blocks' relaxed atomics visible across non-coherent per-XCD L2s (phase-3
// read counts as zero -> perplexity=1). The fix (device-scope release fence
// after the epilogue) is exactly the operation R7 measured at 15-30us of
// L2-writeback stall — more than the ~10us dispatch saving. Axis closed.
// Structure summary of everything proven across R0-R16:
//   - shared-init first, one cheap barrier; staging->convert->chunks
//     BARRIER-FREE per wave (staging is wave-local; R15 +2us)
//   - chunk loop: reg ping-pong B dbuf (b0/b1 named), setprio MFMA cluster,
//     3-term single-chain bf16 split (R9/R14/R15; 64->48 MFMA/chunk)
//   - tail: relaxed atomics BEFORE epilogue (R0 ordering; ordered/ticket
//     variants cost 15-30us, R6/R7); zero-count bins skipped
//   - epilogue: ping-pong [64][65] tiles, gather(s+1) overlaps scatter(s)
__global__ __launch_bounds__(256, 2) void vq_main(const float* __restrict__ in,
                                                  const float* __restrict__ emb,
                                                  float* __restrict__ out,
                                                  float* __restrict__ ws) {
    __shared__ __align__(16) float xs[256 * 68];  // x [pix][d] pad-68; reused as 2 q-tiles
    __shared__ float    x2_lds[256];
    __shared__ float    nrm_lds[KCODES];
    __shared__ int      idx_lds[256];
    __shared__ unsigned cnt_lds[KCODES];
    __shared__ float    red_tot;

    const int t = threadIdx.x;
    const int l = t & 63, wid = t >> 6;   // wave handles pixels [wid*64, +64)

    const int pix0 = blockIdx.x << 8;
    const int b    = pix0 >> 12;
    const int hwb  = pix0 & (HWSZ - 1);

    // Shared init FIRST: cnt zero + red_tot + norms; one cheap barrier with
    // only 2 loads/thread in flight. Everything after is wave-local until
    // the post-argmin reduce.
    cnt_lds[t] = 0u; cnt_lds[t + 256] = 0u;
    if (t == 0) red_tot = 0.f;
    nrm_lds[t]       = ws[WS_NRM_OFF + t];
    nrm_lds[t + 256] = ws[WS_NRM_OFF + t + 256];
    __syncthreads();

    // Chunk-0 B-frags issued next: their L2 latency hides under the 64
    // staging loads below (R14-proven placement, bit-exact).
    const uint4* fragp = reinterpret_cast<const uint4*>(ws + WS_FRAG_F32);
    uint4 b0[8], b1[8];
#pragma unroll
    for (int i = 0; i < 8; ++i) {
        int ct = i >> 2, ks = (i >> 1) & 1, h = i & 1;
        b0[i] = fragp[(((ct) * 2 + ks) * 2 + h) * 64 + l];
    }

    // Stage x (thread t = pixel t): coalesced global reads, b128 LDS writes.
    // Wave-local: no barrier needed before consuming xs (intra-wave lgkmcnt
    // ordering is compiler-handled).
    const float* inb = in + b * (DDIM * HWSZ) + hwb + t;
    float x2 = 0.f;
#pragma unroll
    for (int c = 0; c < DDIM; c += 4) {
        float4 v;
        v.x = inb[(c + 0) * HWSZ]; v.y = inb[(c + 1) * HWSZ];
        v.z = inb[(c + 2) * HWSZ]; v.w = inb[(c + 3) * HWSZ];
        *reinterpret_cast<float4*>(&xs[t * 68 + c]) = v;
        x2 = fmaf(v.x, v.x, x2); x2 = fmaf(v.y, v.y, x2);
        x2 = fmaf(v.z, v.z, x2); x2 = fmaf(v.w, v.w, x2);
    }
    x2_lds[t] = x2;

    // A-fragments (A[m][k]: m=lane&15, k=(lane>>4)*8+j), hi/lo bf16 split.
    bf16x8 a_hi[4][2], a_lo[4][2];
#pragma unroll
    for (int pt = 0; pt < 4; ++pt)
#pragma unroll
    for (int ks = 0; ks < 2; ++ks) {
        int pixl = wid * 64 + pt * 16 + (l & 15);
        int d0   = ks * 32 + ((l >> 4) & 3) * 8;
        const float4* p = reinterpret_cast<const float4*>(&xs[pixl * 68 + d0]);
        float4 f0 = p[0], f1 = p[1];
        float fv[8] = {f0.x, f0.y, f0.z, f0.w, f1.x, f1.y, f1.z, f1.w};
        bf16x8 h8, l8;
#pragma unroll
        for (int j = 0; j < 8; ++j) {
            __bf16 hb = (__bf16)fv[j];
            h8[j] = hb;
            l8[j] = (__bf16)(fv[j] - (float)hb);
        }
        a_hi[pt][ks] = h8; a_lo[pt][ks] = l8;
    }

    float best[4][4]; int bidx[4][4];
#pragma unroll
    for (int pt = 0; pt < 4; ++pt)
#pragma unroll
    for (int r = 0; r < 4; ++r) { best[pt][r] = 3.4e38f; bidx[pt][r] = 0; }

#pragma unroll 1
    for (int c = 0; c < 16; c += 2) {
        vq_chunk(c,     true,         fragp, l, b0, b1, a_hi, a_lo, nrm_lds, best, bidx);
        vq_chunk(c + 1, (c + 1) < 15, fragp, l, b1, b0, a_hi, a_lo, nrm_lds, best, bidx);
    }

    // Cross-lane argmin within each 16-lane group (codes spread over lane&15);
    // (dist, then idx) min = exact first-min semantics.
#pragma unroll
    for (int off = 1; off < 16; off <<= 1) {
#pragma unroll
        for (int pt = 0; pt < 4; ++pt)
#pragma unroll
        for (int r = 0; r < 4; ++r) {
            float ob = __shfl_xor(best[pt][r], off, 64);
            int   oi = __shfl_xor(bidx[pt][r], off, 64);
            bool take = (ob < best[pt][r]) || (ob == best[pt][r] && oi < bidx[pt][r]);
            if (take) { best[pt][r] = ob; bidx[pt][r] = oi; }
        }
    }
    if ((l & 15) == 0) {
        int q = l >> 4;
        float lp = 0.f;
#pragma unroll
        for (int pt = 0; pt < 4; ++pt)
#pragma unroll
        for (int r = 0; r < 4; ++r) {
            int pixl = wid * 64 + pt * 16 + q * 4 + r;
            idx_lds[pixl] = bidx[pt][r];
            atomicAdd(&cnt_lds[bidx[pt][r]], 1u);
            lp += x2_lds[pixl] + best[pt][r];   // |x-e|^2 = x^2 + (|e|^2 - 2x.e)
        }
        atomicAdd(&red_tot, lp);
    }
    __syncthreads();

    // Relaxed global atomics issued before the epilogue (R0 ordering): they
    // drain at the first epilogue barrier, overlapped with the gather phase.
    // Zero-count bins skipped (bit-exact; >=50% fewer atomics).
    if (t == 0) atomicAdd(ws, red_tot);
    unsigned* gcnt = reinterpret_cast<unsigned*>(ws) + WS_CNT_OFF;
    {
        unsigned cv0 = cnt_lds[t];       if (cv0) atomicAdd(gcnt + t, cv0);
        unsigned cv1 = cnt_lds[t + 256]; if (cv1) atomicAdd(gcnt + t + 256, cv1);
    }

    // Epilogue — ping-pong tiles (R13/R14-proven): tile ptr = xs + (s&1)*4160;
    // gather(s+1) overlaps scatter(s); one barrier per slice; bit-exact.
    float* out2 = out + OUT_NCHW_OFF;   // NCHW
    float* out3 = out + OUT_NHWC_OFF;   // NHWC flat (float2-aligned)
    const float2* emb2 = reinterpret_cast<const float2*>(emb);
    float2* out3_2 = reinterpret_cast<float2*>(out3);

#define GATHER(S)                                                              \
    {                                                                          \
        float* qt = xs + ((S) & 1) * (64 * 65);                                \
        _Pragma("unroll")                                                      \
        for (int it = 0; it < 8; ++it) {                                       \
            int fid = it * 256 + t;                                            \
            int pp  = fid >> 5;                                                \
            int c2  = fid & 31;                                                \
            int row = idx_lds[(S) * 64 + pp];                                  \
            float2 v = emb2[row * 32 + c2];                                    \
            out3_2[(size_t)(pix0 + (S) * 64 + pp) * 32 + c2] = v;              \
            qt[pp * 65 + c2 * 2 + 0] = v.x;                                    \
            qt[pp * 65 + c2 * 2 + 1] = v.y;                                    \
        }                                                                      \
    }
#define SCATTER(S)                                                             \
    {                                                                          \
        float* qt = xs + ((S) & 1) * (64 * 65);                                \
        _Pragma("unroll")                                                      \
        for (int it = 0; it < 16; ++it) {                                      \
            int did = it * 256 + t;                                            \
            int c   = did >> 6;                                                \
            int hwl = did & 63;                                                \
            out2[(size_t)(b * DDIM + c) * HWSZ + hwb + (S) * 64 + hwl] =       \
                qt[hwl * 65 + c];                                              \
        }                                                                      \
    }

    GATHER(0);
    __syncthreads();
#pragma unroll 1
    for (int s = 0; s < 4; ++s) {
        if (s < 3) GATHER(s + 1);
        SCATTER(s);
        __syncthreads();
    }
#undef GATHER
#undef SCATTER
}

__global__ __launch_bounds__(256) void vq_fin(float* __restrict__ out,
                                              const float* __restrict__ ws) {
    const unsigned* cnt = reinterpret_cast<const unsigned*>(ws) + WS_CNT_OFF;
    int t = threadIdx.x;  // 256
    double s = 0.0;
#pragma unroll
    for (int k = t; k < KCODES; k += 256) {
        double p = (double)cnt[k] / (double)NPIX;
        s += p * log(p + 1e-10);
    }
#pragma unroll
    for (int o = 32; o > 0; o >>= 1) s += __shfl_xor(s, o, 64);
    __shared__ double rd[4];
    if ((t & 63) == 0) rd[t >> 6] = s;
    __syncthreads();
    if (t == 0) {
        double tot = rd[0] + rd[1] + rd[2] + rd[3];
        out[OUT_PERP_IDX] = (float)exp(-tot);
        out[0] = 0.25f * ws[0] / (float)NELEM;
    }
}

extern "C" void kernel_launch(void* const* d_in, const int* in_sizes, int n_in,
                              void* d_out, int out_size, void* d_ws, size_t ws_size,
                              hipStream_t stream) {
    const float* in  = (const float*)d_in[0];
    const float* emb = (const float*)d_in[1];
    float* out = (float*)d_out;
    float* ws  = (float*)d_ws;

    // vq_prep zeroes loss+counts and overwrites norms + frag region:
    // no memset dispatch needed. Kernel boundaries provide cross-block
    // ordering (in-kernel tickets/coop fences proven to cost 15-30us or
    // fail coherence, R6/R7/R16).
    vq_prep<<<32, 256, 0, stream>>>(emb, ws);
    vq_main<<<NBLOCKS, 256, 0, stream>>>(in, emb, out, ws);
    vq_fin<<<1, 256, 0, stream>>>(out, ws);
}